// Round 13
// baseline (9271.344 us; speedup 1.0000x reference)
//
#include <hip/hip_runtime.h>

#define TT 4096

typedef __attribute__((ext_vector_type(2))) unsigned int u2v;
typedef __attribute__((ext_vector_type(4))) unsigned int u4v;
typedef __attribute__((ext_vector_type(2))) __fp16 f16x2;
typedef __attribute__((ext_vector_type(2))) _Float16 F16x2;
union HU { unsigned int u; f16x2 hf; F16x2 hF; };

// ws layout (float offsets):
//   M    @ 0      : 2048*64 = 131072   (W_in @ C)
//   wtil @ 131072 : 64                 (C^T @ dense_W[:64])
//   yp   @ 131200 : 4096*64 = 262144   (per-WG dense partials, plain stores)
//   hpub @ 393344 : 2 slots * 1024 packets * (u32 data, u32 tag) = 4096 u32
// hpub needs NO init: harness poisons ws to 0xAA -> tag never matches t+1.
//
// LAWS (confirmed): publish = ONE coalesced burst from ONE wave after a
// gather barrier (r1/r2/r6). Publisher wave != poller wave (r9, +500us).
// FALSIFIED: reader contention via replication (r2/r4), poll sampling
// quantization (r7 -- detect is NOT k*RT quantized), nt/MALL (r8).
// CURSED: 256-thread multi-row restructure (r11/r12) -- identical absmax
// across two different reduces => esn_recur had no effect; unverifiable
// headless. 1024-thread r9 skeleton is frozen.
// r13 THEORY: residual ~4300cy of exchange = store VISIBILITY inflated by
// writer-vs-reader line contention (64 polling waves x 16 sc0sc1 loads
// hammer the 128 board lines continuously; the publish store must win
// line access against that). r7's null is consistent: faster sampling
// can't help if polling itself delays arrival. FIX: throttle -- s_sleep 16
// (~1024cy) before the first sample (quiet fabric during the visibility
// window), s_sleep 2 between retry rounds. Value-gated protocol: sleeps
// can only delay detection, never corrupt.

__global__ void esn_prep(const float* __restrict__ C,
                         const float* __restrict__ Win,
                         const float* __restrict__ dW,
                         float* __restrict__ M,
                         float* __restrict__ wtil) {
  __shared__ float s[64];
  const int b = blockIdx.x, i = threadIdx.x;
  if (b < 2048) {
    s[i] = Win[b * 64 + i];
    __syncthreads();
    float acc = 0.f;
#pragma unroll 16
    for (int d = 0; d < 64; ++d) acc += s[d] * C[d * 64 + i];
    M[b * 64 + i] = acc;
  } else {
    s[i] = dW[i];
    __syncthreads();
    float acc = 0.f;
    for (int d = 0; d < 64; ++d) acc += s[d] * C[d * 64 + i];
    wtil[i] = acc;
  }
}

// Call-free tanh: tanh(x) = 1 - 2/(exp(2x)+1)
__device__ __forceinline__ float fast_tanh(float x) {
  const float e = __builtin_amdgcn_exp2f(x * 2.8853900817779268f);  // exp(2x)
  return 1.0f - 2.0f * __builtin_amdgcn_rcpf(e + 1.0f);
}

// fp16-pair dot with fp32 accumulate: v_dot2_f32_f16 where available.
__device__ __forceinline__ float fdot2f(const HU a, const HU b, float c) {
#if __has_builtin(__builtin_amdgcn_fdot2)
  return __builtin_amdgcn_fdot2(a.hF, b.hF, c, false);
#else
  return c + (float)a.hf.x * (float)b.hf.x + (float)a.hf.y * (float)b.hf.y;
#endif
}

// 64 WGs x 1024 threads; WG owns 32 rows (2/wave); W in VGPRs (r3 proven).
// = r9 (9116us, proven) + poll pacing (s_sleep) ONLY.
__global__ __launch_bounds__(1024) void esn_recur(
    const float* __restrict__ X, const float* __restrict__ M,
    const float* __restrict__ W, const float* __restrict__ dW,
    unsigned int* __restrict__ hpub, float* __restrict__ yp) {
  __shared__ unsigned int shh[1024];  // 2048 fp16 h as packed pairs
  __shared__ unsigned int pub[16];    // per-wave packed h pairs
  __shared__ float psm[16];           // per-wave dense partials
  const int tid = threadIdx.x;
  const int lane = tid & 63;
  const int wave = tid >> 6;
  const int b = blockIdx.x;
  const int r0 = b * 32 + wave * 2;
  const float m0 = M[r0 * 64 + lane];
  const float m1 = M[(r0 + 1) * 64 + lane];
  const float dw0 = dW[64 + r0];
  const float dw1 = dW[64 + r0 + 1];
  // one-time: this lane's W fragment -> 32 persistent VGPRs (packed fp16).
  u4v wA[4], wB[4];
#pragma unroll
  for (int j = 0; j < 4; ++j) {
    const float* p0 = W + (size_t)r0 * 2048 + 512 * j + 8 * lane;
    const float* p1 = p0 + 2048;
    const float4 a = *(const float4*)p0;
    const float4 c = *(const float4*)(p0 + 4);
    const float4 d = *(const float4*)p1;
    const float4 e = *(const float4*)(p1 + 4);
    HU t0, t1, t2, t3;
    t0.hf = __builtin_amdgcn_cvt_pkrtz(a.x, a.y);
    t1.hf = __builtin_amdgcn_cvt_pkrtz(a.z, a.w);
    t2.hf = __builtin_amdgcn_cvt_pkrtz(c.x, c.y);
    t3.hf = __builtin_amdgcn_cvt_pkrtz(c.z, c.w);
    wA[j][0] = t0.u; wA[j][1] = t1.u; wA[j][2] = t2.u; wA[j][3] = t3.u;
    t0.hf = __builtin_amdgcn_cvt_pkrtz(d.x, d.y);
    t1.hf = __builtin_amdgcn_cvt_pkrtz(d.z, d.w);
    t2.hf = __builtin_amdgcn_cvt_pkrtz(e.x, e.y);
    t3.hf = __builtin_amdgcn_cvt_pkrtz(e.z, e.w);
    wB[j][0] = t0.u; wB[j][1] = t1.u; wB[j][2] = t2.u; wB[j][3] = t3.u;
  }
  shh[tid] = 0u;  // h_{-1} = 0
  __syncthreads();

  float xv = X[lane];

  for (int t = 0; t < TT; ++t) {
    // ---- compute 2 rows/wave: W from VGPR, h from LDS ----
    float a0 = m0 * xv, a1 = m1 * xv;
#pragma unroll
    for (int j = 0; j < 4; ++j) {
      const u4v hv = *(const u4v*)(shh + 4 * lane + 256 * j);
#pragma unroll
      for (int k = 0; k < 4; ++k) {
        HU ha, wa, wb;
        ha.u = hv[k]; wa.u = wA[j][k]; wb.u = wB[j][k];
        a0 = fdot2f(wa, ha, a0);
        a1 = fdot2f(wb, ha, a1);
      }
    }
#pragma unroll
    for (int off = 32; off; off >>= 1) {
      a0 += __shfl_xor(a0, off, 64);
      a1 += __shfl_xor(a1, off, 64);
    }
    if (lane == 0) {
      const float h0 = fast_tanh(a0);
      const float h1 = fast_tanh(a1);
      HU pk; pk.hf = __builtin_amdgcn_cvt_pkrtz(h0, h1);
      pub[wave] = pk.u;
      psm[wave] = dw0 * h0 + dw1 * h1;
    }
    __syncthreads();  // bar1: pub + psm ready; all shh reads of step t done
    const unsigned tg = (unsigned)t + 1u;
    unsigned int* slot = hpub + ((t & 1) << 11);
    // X prefetch for t+1: latency hides under poll / bar2 slack (r9).
    const int tn = (t + 1 < TT) ? t + 1 : t;
    const float xnext = X[tn * 64 + lane];
    if (wave == 1) {
      // publish: ONE coalesced 16-packet burst from wave1 (NOT the poller).
      if (t + 1 < TT && lane < 16) {
        u2v pv; pv.x = pub[lane]; pv.y = tg;
        asm volatile("global_store_dwordx2 %0, %1, off sc0 sc1"
                     :: "v"(slot + 2 * (16 * b + lane)), "v"(pv) : "memory");
      }
    } else if (wave == 0) {
      if (t + 1 < TT) {
        // pacing: quiet fabric during the store-visibility window
        asm volatile("s_sleep 16" ::: "memory");
        // poll: lane L owns packets {64p+L}; 16 loads in flight per round;
        // vmcnt(0) drains loads only -- never a store ack (r9 law).
        const unsigned int* b0 = slot + 2 * lane;
        const unsigned int* b1 = b0 + 1024;
        u2v q0, q1, q2, q3, q4, q5, q6, q7, q8, q9, qa, qb, qc, qd, qe, qf;
        for (;;) {
          asm volatile(
              "global_load_dwordx2 %0, %16, off sc0 sc1\n\t"
              "global_load_dwordx2 %1, %16, off offset:512 sc0 sc1\n\t"
              "global_load_dwordx2 %2, %16, off offset:1024 sc0 sc1\n\t"
              "global_load_dwordx2 %3, %16, off offset:1536 sc0 sc1\n\t"
              "global_load_dwordx2 %4, %16, off offset:2048 sc0 sc1\n\t"
              "global_load_dwordx2 %5, %16, off offset:2560 sc0 sc1\n\t"
              "global_load_dwordx2 %6, %16, off offset:3072 sc0 sc1\n\t"
              "global_load_dwordx2 %7, %16, off offset:3584 sc0 sc1\n\t"
              "global_load_dwordx2 %8, %17, off sc0 sc1\n\t"
              "global_load_dwordx2 %9, %17, off offset:512 sc0 sc1\n\t"
              "global_load_dwordx2 %10, %17, off offset:1024 sc0 sc1\n\t"
              "global_load_dwordx2 %11, %17, off offset:1536 sc0 sc1\n\t"
              "global_load_dwordx2 %12, %17, off offset:2048 sc0 sc1\n\t"
              "global_load_dwordx2 %13, %17, off offset:2560 sc0 sc1\n\t"
              "global_load_dwordx2 %14, %17, off offset:3072 sc0 sc1\n\t"
              "global_load_dwordx2 %15, %17, off offset:3584 sc0 sc1\n\t"
              "s_waitcnt vmcnt(0)"
              : "=&v"(q0), "=&v"(q1), "=&v"(q2), "=&v"(q3),
                "=&v"(q4), "=&v"(q5), "=&v"(q6), "=&v"(q7),
                "=&v"(q8), "=&v"(q9), "=&v"(qa), "=&v"(qb),
                "=&v"(qc), "=&v"(qd), "=&v"(qe), "=&v"(qf)
              : "v"(b0), "v"(b1)
              : "memory");
          bool ok = (q0.y == tg) && (q1.y == tg) && (q2.y == tg) &&
                    (q3.y == tg) && (q4.y == tg) && (q5.y == tg) &&
                    (q6.y == tg) && (q7.y == tg) && (q8.y == tg) &&
                    (q9.y == tg) && (qa.y == tg) && (qb.y == tg) &&
                    (qc.y == tg) && (qd.y == tg) && (qe.y == tg) &&
                    (qf.y == tg);
          if (__all(ok)) break;
          asm volatile("s_sleep 2" ::: "memory");  // retry pacing
        }
        // repack: shh[64p + lane] -- stride-1 across lanes, conflict-free
        shh[lane] = q0.x;          shh[64 + lane] = q1.x;
        shh[128 + lane] = q2.x;    shh[192 + lane] = q3.x;
        shh[256 + lane] = q4.x;    shh[320 + lane] = q5.x;
        shh[384 + lane] = q6.x;    shh[448 + lane] = q7.x;
        shh[512 + lane] = q8.x;    shh[576 + lane] = q9.x;
        shh[640 + lane] = qa.x;    shh[704 + lane] = qb.x;
        shh[768 + lane] = qc.x;    shh[832 + lane] = qd.x;
        shh[896 + lane] = qe.x;    shh[960 + lane] = qf.x;
      }
    } else if (tid == 128) {
      // dense partial for step t (wave2 lane0; parallel with publish+poll)
      float s = 0.f;
#pragma unroll
      for (int wv = 0; wv < 16; ++wv) s += psm[wv];
      yp[t * 64 + b] = s;
    }
    __syncthreads();  // bar2: shh now holds h_t
    xv = xnext;
  }
}

__global__ void esn_out(const float* __restrict__ X,
                        const float* __restrict__ wtil,
                        const float* __restrict__ yp,
                        const float* __restrict__ bptr,
                        float* __restrict__ out) {
  const int tid = threadIdx.x;
  const int lane = tid & 63;
  const int wave = tid >> 6;
  const int t = blockIdx.x * 4 + wave;
  float v = wtil[lane] * X[t * 64 + lane] + yp[t * 64 + lane];
#pragma unroll
  for (int off = 32; off; off >>= 1) v += __shfl_xor(v, off, 64);
  if (lane == 0) out[t] = v + bptr[0];
}

extern "C" void kernel_launch(void* const* d_in, const int* in_sizes, int n_in,
                              void* d_out, int out_size, void* d_ws, size_t ws_size,
                              hipStream_t stream) {
  const float* X   = (const float*)d_in[0];
  const float* C   = (const float*)d_in[1];
  const float* Win = (const float*)d_in[2];
  const float* W   = (const float*)d_in[3];
  const float* dW  = (const float*)d_in[4];
  const float* db  = (const float*)d_in[5];
  float* ws   = (float*)d_ws;
  float* M    = ws;
  float* wtil = ws + 131072;
  float* yp   = ws + 131200;
  unsigned int* hpub = (unsigned int*)(ws + 393344);

  esn_prep<<<2049, 64, 0, stream>>>(C, Win, dW, M, wtil);

  void* args[] = {(void*)&X, (void*)&M, (void*)&W, (void*)&dW,
                  (void*)&hpub, (void*)&yp};
  (void)hipLaunchCooperativeKernel(reinterpret_cast<void*>(&esn_recur), dim3(64),
                                   dim3(1024), args, 0, stream);

  esn_out<<<1024, 256, 0, stream>>>(X, wtil, yp, db, (float*)d_out);
}

// Round 14
// 8756.946 us; speedup vs baseline: 1.0587x; 1.0587x over previous
//
#include <hip/hip_runtime.h>

#define TT 4096

typedef __attribute__((ext_vector_type(2))) unsigned int u2v;
typedef __attribute__((ext_vector_type(4))) unsigned int u4v;
typedef __attribute__((ext_vector_type(2))) __fp16 f16x2;
typedef __attribute__((ext_vector_type(2))) _Float16 F16x2;
union HU { unsigned int u; f16x2 hf; F16x2 hF; };

// ws layout (float offsets):
//   M    @ 0      : 2048*64 = 131072   (W_in @ C)
//   wtil @ 131072 : 64                 (C^T @ dense_W[:64])
//   yp   @ 131200 : 4096*64 = 262144   (per-WG dense partials, plain stores)
//   hpub @ 393344 : 2 slots * 1024 packets * (u32 data, u32 tag) = 4096 u32
// hpub needs NO init: harness poisons ws to 0xAA -> tag never matches t+1.
//
// LAWS (confirmed): publish = ONE coalesced burst from ONE wave after a
// gather barrier (r1/r2/r6). Publisher wave != poller wave (r9, -500us).
// FALSIFIED: reader contention -- replication (r2/r4) AND throttling
// (r13: s_sleep pacing lowered FETCH but RAISED dur); poll sampling
// quantization (r7); nt/MALL (r8); barrier vmcnt drains (r7).
// CURSED: 256-thread restructure (r11/r12, launch-level no-effect).
// r14 THEORY: the shfl_xor butterfly = 12 cross-lane LDS ops x 16 waves
// = 192 ops x ~5.8cy ~= 1100cy CU-serialized wall on the bar2->publish
// critical path (never attacked). Half-wave-per-row layout halves it:
// row0 on lanes 0-31, row1 on lanes 32-63; reduce = 5 in-half xors + 1
// cross-half swap = 6 ops. h-reads broadcast (halves read same addrs),
// W stays 32 VGPR/lane. Exchange block byte-identical to r9.

__global__ void esn_prep(const float* __restrict__ C,
                         const float* __restrict__ Win,
                         const float* __restrict__ dW,
                         float* __restrict__ M,
                         float* __restrict__ wtil) {
  __shared__ float s[64];
  const int b = blockIdx.x, i = threadIdx.x;
  if (b < 2048) {
    s[i] = Win[b * 64 + i];
    __syncthreads();
    float acc = 0.f;
#pragma unroll 16
    for (int d = 0; d < 64; ++d) acc += s[d] * C[d * 64 + i];
    M[b * 64 + i] = acc;
  } else {
    s[i] = dW[i];
    __syncthreads();
    float acc = 0.f;
    for (int d = 0; d < 64; ++d) acc += s[d] * C[d * 64 + i];
    wtil[i] = acc;
  }
}

// Call-free tanh: tanh(x) = 1 - 2/(exp(2x)+1)
__device__ __forceinline__ float fast_tanh(float x) {
  const float e = __builtin_amdgcn_exp2f(x * 2.8853900817779268f);  // exp(2x)
  return 1.0f - 2.0f * __builtin_amdgcn_rcpf(e + 1.0f);
}

// fp16-pair dot with fp32 accumulate: v_dot2_f32_f16 where available.
__device__ __forceinline__ float fdot2f(const HU a, const HU b, float c) {
#if __has_builtin(__builtin_amdgcn_fdot2)
  return __builtin_amdgcn_fdot2(a.hF, b.hF, c, false);
#else
  return c + (float)a.hf.x * (float)b.hf.x + (float)a.hf.y * (float)b.hf.y;
#endif
}

// 64 WGs x 1024 threads; WG owns 32 rows (2/wave, one per 32-lane half);
// W in VGPRs. Exchange = r9 verbatim.
__global__ __launch_bounds__(1024) void esn_recur(
    const float* __restrict__ X, const float* __restrict__ M,
    const float* __restrict__ W, const float* __restrict__ dW,
    unsigned int* __restrict__ hpub, float* __restrict__ yp) {
  __shared__ unsigned int shh[1024];  // 2048 fp16 h as packed pairs
  __shared__ unsigned int pub[16];    // per-wave packed h pairs
  __shared__ float psm[16];           // per-wave dense partials
  const int tid = threadIdx.x;
  const int lane = tid & 63;
  const int wave = tid >> 6;
  const int b = blockIdx.x;
  const int half = lane >> 5;         // 0 -> row r0, 1 -> row r0+1
  const int li = lane & 31;
  const int r0 = b * 32 + wave * 2;
  const int row = r0 + half;
  // M.x term split across the half: lane li covers d=li and d=li+32
  const float ma = M[row * 64 + li];
  const float mb = M[row * 64 + li + 32];
  const float dw0 = dW[64 + r0];
  const float dw1 = dW[64 + r0 + 1];
  // one-time: lane li of each half holds ITS row's pair-chunks {4li+128m},
  // m=0..7 -> fp32 elements [8li+256m .. +7]: two float4 per m. 32 VGPRs.
  u4v w[8];
#pragma unroll
  for (int m = 0; m < 8; ++m) {
    const float* p = W + (size_t)row * 2048 + 256 * m + 8 * li;
    const float4 a = *(const float4*)p;
    const float4 c = *(const float4*)(p + 4);
    HU t0, t1, t2, t3;
    t0.hf = __builtin_amdgcn_cvt_pkrtz(a.x, a.y);
    t1.hf = __builtin_amdgcn_cvt_pkrtz(a.z, a.w);
    t2.hf = __builtin_amdgcn_cvt_pkrtz(c.x, c.y);
    t3.hf = __builtin_amdgcn_cvt_pkrtz(c.z, c.w);
    w[m][0] = t0.u; w[m][1] = t1.u; w[m][2] = t2.u; w[m][3] = t3.u;
  }
  shh[tid] = 0u;  // h_{-1} = 0
  __syncthreads();

  float xa = X[li];
  float xb = X[li + 32];

  for (int t = 0; t < TT; ++t) {
    // ---- compute: each half-wave computes one full row ----
    float acc = ma * xa + mb * xb;
#pragma unroll
    for (int m = 0; m < 8; ++m) {
      // lanes li and li+32 read the same address -> LDS broadcast (free);
      // across li: 16B stride -> conflict-free ds_read_b128.
      const u4v hv = *(const u4v*)(shh + 4 * li + 128 * m);
#pragma unroll
      for (int k = 0; k < 4; ++k) {
        HU ha, wv;
        ha.u = hv[k]; wv.u = w[m][k];
        acc = fdot2f(wv, ha, acc);
      }
    }
    // ---- reduce: 5 in-half xor steps + 1 cross-half swap (6 vs 12) ----
#pragma unroll
    for (int off = 16; off; off >>= 1) acc += __shfl_xor(acc, off, 64);
    const float other = __shfl_xor(acc, 32, 64);  // lane0: row1's sum
    if (lane == 0) {
      const float h0 = fast_tanh(acc);
      const float h1 = fast_tanh(other);
      HU pk; pk.hf = __builtin_amdgcn_cvt_pkrtz(h0, h1);
      pub[wave] = pk.u;
      psm[wave] = dw0 * h0 + dw1 * h1;
    }
    __syncthreads();  // bar1: pub + psm ready; all shh reads of step t done
    const unsigned tg = (unsigned)t + 1u;
    unsigned int* slot = hpub + ((t & 1) << 11);
    // X prefetch for t+1: latency hides under poll / bar2 slack (r9).
    const int tn = (t + 1 < TT) ? t + 1 : t;
    const float xan = X[tn * 64 + li];
    const float xbn = X[tn * 64 + li + 32];
    if (wave == 1) {
      // publish: ONE coalesced 16-packet burst from wave1 (NOT the poller).
      if (t + 1 < TT && lane < 16) {
        u2v pv; pv.x = pub[lane]; pv.y = tg;
        asm volatile("global_store_dwordx2 %0, %1, off sc0 sc1"
                     :: "v"(slot + 2 * (16 * b + lane)), "v"(pv) : "memory");
      }
    } else if (wave == 0) {
      if (t + 1 < TT) {
        // poll: lane L owns packets {64p+L}; 16 loads in flight per round;
        // vmcnt(0) drains loads only -- never a store ack (r9 law).
        const unsigned int* b0 = slot + 2 * lane;
        const unsigned int* b1 = b0 + 1024;
        u2v q0, q1, q2, q3, q4, q5, q6, q7, q8, q9, qa, qb, qc, qd, qe, qf;
        for (;;) {
          asm volatile(
              "global_load_dwordx2 %0, %16, off sc0 sc1\n\t"
              "global_load_dwordx2 %1, %16, off offset:512 sc0 sc1\n\t"
              "global_load_dwordx2 %2, %16, off offset:1024 sc0 sc1\n\t"
              "global_load_dwordx2 %3, %16, off offset:1536 sc0 sc1\n\t"
              "global_load_dwordx2 %4, %16, off offset:2048 sc0 sc1\n\t"
              "global_load_dwordx2 %5, %16, off offset:2560 sc0 sc1\n\t"
              "global_load_dwordx2 %6, %16, off offset:3072 sc0 sc1\n\t"
              "global_load_dwordx2 %7, %16, off offset:3584 sc0 sc1\n\t"
              "global_load_dwordx2 %8, %17, off sc0 sc1\n\t"
              "global_load_dwordx2 %9, %17, off offset:512 sc0 sc1\n\t"
              "global_load_dwordx2 %10, %17, off offset:1024 sc0 sc1\n\t"
              "global_load_dwordx2 %11, %17, off offset:1536 sc0 sc1\n\t"
              "global_load_dwordx2 %12, %17, off offset:2048 sc0 sc1\n\t"
              "global_load_dwordx2 %13, %17, off offset:2560 sc0 sc1\n\t"
              "global_load_dwordx2 %14, %17, off offset:3072 sc0 sc1\n\t"
              "global_load_dwordx2 %15, %17, off offset:3584 sc0 sc1\n\t"
              "s_waitcnt vmcnt(0)"
              : "=&v"(q0), "=&v"(q1), "=&v"(q2), "=&v"(q3),
                "=&v"(q4), "=&v"(q5), "=&v"(q6), "=&v"(q7),
                "=&v"(q8), "=&v"(q9), "=&v"(qa), "=&v"(qb),
                "=&v"(qc), "=&v"(qd), "=&v"(qe), "=&v"(qf)
              : "v"(b0), "v"(b1)
              : "memory");
          bool ok = (q0.y == tg) && (q1.y == tg) && (q2.y == tg) &&
                    (q3.y == tg) && (q4.y == tg) && (q5.y == tg) &&
                    (q6.y == tg) && (q7.y == tg) && (q8.y == tg) &&
                    (q9.y == tg) && (qa.y == tg) && (qb.y == tg) &&
                    (qc.y == tg) && (qd.y == tg) && (qe.y == tg) &&
                    (qf.y == tg);
          if (__all(ok)) break;
        }
        // repack: shh[64p + lane] -- stride-1 across lanes, conflict-free
        shh[lane] = q0.x;          shh[64 + lane] = q1.x;
        shh[128 + lane] = q2.x;    shh[192 + lane] = q3.x;
        shh[256 + lane] = q4.x;    shh[320 + lane] = q5.x;
        shh[384 + lane] = q6.x;    shh[448 + lane] = q7.x;
        shh[512 + lane] = q8.x;    shh[576 + lane] = q9.x;
        shh[640 + lane] = qa.x;    shh[704 + lane] = qb.x;
        shh[768 + lane] = qc.x;    shh[832 + lane] = qd.x;
        shh[896 + lane] = qe.x;    shh[960 + lane] = qf.x;
      }
    } else if (tid == 128) {
      // dense partial for step t (wave2 lane0; parallel with publish+poll)
      float s = 0.f;
#pragma unroll
      for (int wv = 0; wv < 16; ++wv) s += psm[wv];
      yp[t * 64 + b] = s;
    }
    __syncthreads();  // bar2: shh now holds h_t
    xa = xan;
    xb = xbn;
  }
}

__global__ void esn_out(const float* __restrict__ X,
                        const float* __restrict__ wtil,
                        const float* __restrict__ yp,
                        const float* __restrict__ bptr,
                        float* __restrict__ out) {
  const int tid = threadIdx.x;
  const int lane = tid & 63;
  const int wave = tid >> 6;
  const int t = blockIdx.x * 4 + wave;
  float v = wtil[lane] * X[t * 64 + lane] + yp[t * 64 + lane];
#pragma unroll
  for (int off = 32; off; off >>= 1) v += __shfl_xor(v, off, 64);
  if (lane == 0) out[t] = v + bptr[0];
}

extern "C" void kernel_launch(void* const* d_in, const int* in_sizes, int n_in,
                              void* d_out, int out_size, void* d_ws, size_t ws_size,
                              hipStream_t stream) {
  const float* X   = (const float*)d_in[0];
  const float* C   = (const float*)d_in[1];
  const float* Win = (const float*)d_in[2];
  const float* W   = (const float*)d_in[3];
  const float* dW  = (const float*)d_in[4];
  const float* db  = (const float*)d_in[5];
  float* ws   = (float*)d_ws;
  float* M    = ws;
  float* wtil = ws + 131072;
  float* yp   = ws + 131200;
  unsigned int* hpub = (unsigned int*)(ws + 393344);

  esn_prep<<<2049, 64, 0, stream>>>(C, Win, dW, M, wtil);

  void* args[] = {(void*)&X, (void*)&M, (void*)&W, (void*)&dW,
                  (void*)&hpub, (void*)&yp};
  (void)hipLaunchCooperativeKernel(reinterpret_cast<void*>(&esn_recur), dim3(64),
                                   dim3(1024), args, 0, stream);

  esn_out<<<1024, 256, 0, stream>>>(X, wtil, yp, db, (float*)d_out);
}

// Round 15
// 8755.222 us; speedup vs baseline: 1.0590x; 1.0002x over previous
//
#include <hip/hip_runtime.h>

#define TT 4096

typedef __attribute__((ext_vector_type(2))) unsigned int u2v;
typedef __attribute__((ext_vector_type(4))) unsigned int u4v;
typedef __attribute__((ext_vector_type(2))) __fp16 f16x2;
typedef __attribute__((ext_vector_type(2))) _Float16 F16x2;
union HU { unsigned int u; f16x2 hf; F16x2 hF; };

// ws layout (float offsets):
//   M    @ 0      : 2048*64 = 131072   (W_in @ C)
//   wtil @ 131072 : 64                 (C^T @ dense_W[:64])
//   yp   @ 131200 : 4096*64 = 262144   (per-WG dense partials, plain stores)
//   hpub @ 393344 : 2 slots * 1024 packets * (u32 data, u32 tag) = 4096 u32
// hpub needs NO init: harness poisons ws to 0xAA -> tag never matches t+1.
//
// LAWS (confirmed): publish = ONE coalesced burst from ONE wave after a
// gather barrier (r1/r2/r6). Publisher wave != poller wave (r9, -500us).
// Cross-lane reduce + LDS h-streaming are real walls (r14, -360us).
// FALSIFIED: reader contention (r2/r4 replication, r13 throttling), poll
// sampling quantization (r7), nt/MALL (r8), barrier vmcnt drains (r7).
// CURSED: 256-thread launches (r11/r12).
// r15: quarter-wave layout -- 8 compute waves (8..15), 4 rows/wave, one
// row per 16-lane quarter. Cross-lane ops 96 -> 56; unique h-LDS traffic
// 64KB -> 32KB (4-way broadcast). Role-split t-loops (compute | protocol)
// with equal barrier counts; register pressure separated. Wire format and
// exchange block byte-identical to r14. Packet p <-> rows {2p,2p+1} holds:
// pub[2cw]=rows 4cw,4cw+1; pub[2cw+1]=rows 4cw+2,4cw+3.

__global__ void esn_prep(const float* __restrict__ C,
                         const float* __restrict__ Win,
                         const float* __restrict__ dW,
                         float* __restrict__ M,
                         float* __restrict__ wtil) {
  __shared__ float s[64];
  const int b = blockIdx.x, i = threadIdx.x;
  if (b < 2048) {
    s[i] = Win[b * 64 + i];
    __syncthreads();
    float acc = 0.f;
#pragma unroll 16
    for (int d = 0; d < 64; ++d) acc += s[d] * C[d * 64 + i];
    M[b * 64 + i] = acc;
  } else {
    s[i] = dW[i];
    __syncthreads();
    float acc = 0.f;
    for (int d = 0; d < 64; ++d) acc += s[d] * C[d * 64 + i];
    wtil[i] = acc;
  }
}

// Call-free tanh: tanh(x) = 1 - 2/(exp(2x)+1)
__device__ __forceinline__ float fast_tanh(float x) {
  const float e = __builtin_amdgcn_exp2f(x * 2.8853900817779268f);  // exp(2x)
  return 1.0f - 2.0f * __builtin_amdgcn_rcpf(e + 1.0f);
}

// fp16-pair dot with fp32 accumulate: v_dot2_f32_f16 where available.
__device__ __forceinline__ float fdot2f(const HU a, const HU b, float c) {
#if __has_builtin(__builtin_amdgcn_fdot2)
  return __builtin_amdgcn_fdot2(a.hF, b.hF, c, false);
#else
  return c + (float)a.hf.x * (float)b.hf.x + (float)a.hf.y * (float)b.hf.y;
#endif
}

// 64 WGs x 1024 threads. Waves 8-15 compute (4 rows each, quarter-wave);
// wave0 polls, wave1 publishes, wave2 writes yp; waves 3-7 barrier-idle.
__global__ __launch_bounds__(1024) void esn_recur(
    const float* __restrict__ X, const float* __restrict__ M,
    const float* __restrict__ W, const float* __restrict__ dW,
    unsigned int* __restrict__ hpub, float* __restrict__ yp) {
  __shared__ unsigned int shh[1024];  // 2048 fp16 h as packed pairs
  __shared__ unsigned int pub[16];    // packed h pairs (2 per compute wave)
  __shared__ float psm[8];            // per-compute-wave dense partials
  const int tid = threadIdx.x;
  const int lane = tid & 63;
  const int wave = tid >> 6;
  const int b = blockIdx.x;
  shh[tid] = 0u;  // h_{-1} = 0
  __syncthreads();

  if (wave >= 8) {
    // ================= COMPUTE ROLE =================
    const int cw = wave - 8;       // 0..7
    const int q = lane >> 4;       // quarter 0..3 -> row offset
    const int ql = lane & 15;
    const int row = b * 32 + cw * 4 + q;
    float m[4], dwv[4];
#pragma unroll
    for (int j = 0; j < 4; ++j) m[j] = M[row * 64 + ql + 16 * j];
#pragma unroll
    for (int r = 0; r < 4; ++r) dwv[r] = dW[64 + b * 32 + cw * 4 + r];
    // this lane's W fragment: row's pair-chunks {4ql+64m}, m=0..15
    // -> fp32 elements [8ql+128m .. +7]: two float4 per m. 64 VGPRs.
    u4v w[16];
#pragma unroll
    for (int mm = 0; mm < 16; ++mm) {
      const float* p = W + (size_t)row * 2048 + 128 * mm + 8 * ql;
      const float4 a = *(const float4*)p;
      const float4 c = *(const float4*)(p + 4);
      HU t0, t1, t2, t3;
      t0.hf = __builtin_amdgcn_cvt_pkrtz(a.x, a.y);
      t1.hf = __builtin_amdgcn_cvt_pkrtz(a.z, a.w);
      t2.hf = __builtin_amdgcn_cvt_pkrtz(c.x, c.y);
      t3.hf = __builtin_amdgcn_cvt_pkrtz(c.z, c.w);
      w[mm][0] = t0.u; w[mm][1] = t1.u; w[mm][2] = t2.u; w[mm][3] = t3.u;
    }
    for (int t = 0; t < TT; ++t) {
      // X loads issued at loop top, consumed AFTER the dot phase (~hidden)
      float xr[4];
#pragma unroll
      for (int j = 0; j < 4; ++j) xr[j] = X[t * 64 + ql + 16 * j];
      float acc = 0.f;
#pragma unroll
      for (int mm = 0; mm < 16; ++mm) {
        // lanes ql, ql+16, ql+32, ql+48 read same addr -> 4-way broadcast;
        // across ql: 16B stride -> conflict-free ds_read_b128.
        const u4v hv = *(const u4v*)(shh + 4 * ql + 64 * mm);
#pragma unroll
        for (int k = 0; k < 4; ++k) {
          HU ha, wv;
          ha.u = hv[k]; wv.u = w[mm][k];
          acc = fdot2f(wv, ha, acc);
        }
      }
      acc += m[0] * xr[0] + m[1] * xr[1] + m[2] * xr[2] + m[3] * xr[3];
      // in-quarter reduce (offsets stay within the 16-lane quarter)
#pragma unroll
      for (int off = 8; off; off >>= 1) acc += __shfl_xor(acc, off, 64);
      // gather the 4 quarter-sums to lane 0
      const float s1 = __shfl(acc, 16, 64);
      const float s2 = __shfl(acc, 32, 64);
      const float s3 = __shfl(acc, 48, 64);
      if (lane == 0) {
        const float h0 = fast_tanh(acc);
        const float h1 = fast_tanh(s1);
        const float h2 = fast_tanh(s2);
        const float h3 = fast_tanh(s3);
        HU pa, pb;
        pa.hf = __builtin_amdgcn_cvt_pkrtz(h0, h1);
        pb.hf = __builtin_amdgcn_cvt_pkrtz(h2, h3);
        pub[2 * cw] = pa.u;
        pub[2 * cw + 1] = pb.u;
        psm[cw] = dwv[0] * h0 + dwv[1] * h1 + dwv[2] * h2 + dwv[3] * h3;
      }
      __syncthreads();  // bar1: pub + psm ready; shh reads of step t done
      __syncthreads();  // bar2: shh holds h_t (written by wave0)
    }
  } else {
    // ================= PROTOCOL ROLE =================
    for (int t = 0; t < TT; ++t) {
      __syncthreads();  // bar1
      const unsigned tg = (unsigned)t + 1u;
      unsigned int* slot = hpub + ((t & 1) << 11);
      if (wave == 1) {
        // publish: ONE coalesced 16-packet burst (NOT the poller -- r9 law)
        if (t + 1 < TT && lane < 16) {
          u2v pv; pv.x = pub[lane]; pv.y = tg;
          asm volatile("global_store_dwordx2 %0, %1, off sc0 sc1"
                       :: "v"(slot + 2 * (16 * b + lane)), "v"(pv) : "memory");
        }
      } else if (wave == 0) {
        if (t + 1 < TT) {
          // poll: lane L owns packets {64p+L}; 16 loads in flight/round;
          // vmcnt(0) drains loads only -- never a store ack (r9 law).
          const unsigned int* b0 = slot + 2 * lane;
          const unsigned int* b1 = b0 + 1024;
          u2v q0, q1, q2, q3, q4, q5, q6, q7, q8, q9, qa, qb, qc, qd, qe, qf;
          for (;;) {
            asm volatile(
                "global_load_dwordx2 %0, %16, off sc0 sc1\n\t"
                "global_load_dwordx2 %1, %16, off offset:512 sc0 sc1\n\t"
                "global_load_dwordx2 %2, %16, off offset:1024 sc0 sc1\n\t"
                "global_load_dwordx2 %3, %16, off offset:1536 sc0 sc1\n\t"
                "global_load_dwordx2 %4, %16, off offset:2048 sc0 sc1\n\t"
                "global_load_dwordx2 %5, %16, off offset:2560 sc0 sc1\n\t"
                "global_load_dwordx2 %6, %16, off offset:3072 sc0 sc1\n\t"
                "global_load_dwordx2 %7, %16, off offset:3584 sc0 sc1\n\t"
                "global_load_dwordx2 %8, %17, off sc0 sc1\n\t"
                "global_load_dwordx2 %9, %17, off offset:512 sc0 sc1\n\t"
                "global_load_dwordx2 %10, %17, off offset:1024 sc0 sc1\n\t"
                "global_load_dwordx2 %11, %17, off offset:1536 sc0 sc1\n\t"
                "global_load_dwordx2 %12, %17, off offset:2048 sc0 sc1\n\t"
                "global_load_dwordx2 %13, %17, off offset:2560 sc0 sc1\n\t"
                "global_load_dwordx2 %14, %17, off offset:3072 sc0 sc1\n\t"
                "global_load_dwordx2 %15, %17, off offset:3584 sc0 sc1\n\t"
                "s_waitcnt vmcnt(0)"
                : "=&v"(q0), "=&v"(q1), "=&v"(q2), "=&v"(q3),
                  "=&v"(q4), "=&v"(q5), "=&v"(q6), "=&v"(q7),
                  "=&v"(q8), "=&v"(q9), "=&v"(qa), "=&v"(qb),
                  "=&v"(qc), "=&v"(qd), "=&v"(qe), "=&v"(qf)
                : "v"(b0), "v"(b1)
                : "memory");
            bool ok = (q0.y == tg) && (q1.y == tg) && (q2.y == tg) &&
                      (q3.y == tg) && (q4.y == tg) && (q5.y == tg) &&
                      (q6.y == tg) && (q7.y == tg) && (q8.y == tg) &&
                      (q9.y == tg) && (qa.y == tg) && (qb.y == tg) &&
                      (qc.y == tg) && (qd.y == tg) && (qe.y == tg) &&
                      (qf.y == tg);
            if (__all(ok)) break;
          }
          // repack: shh[64p + lane] -- stride-1 across lanes, conflict-free
          shh[lane] = q0.x;          shh[64 + lane] = q1.x;
          shh[128 + lane] = q2.x;    shh[192 + lane] = q3.x;
          shh[256 + lane] = q4.x;    shh[320 + lane] = q5.x;
          shh[384 + lane] = q6.x;    shh[448 + lane] = q7.x;
          shh[512 + lane] = q8.x;    shh[576 + lane] = q9.x;
          shh[640 + lane] = qa.x;    shh[704 + lane] = qb.x;
          shh[768 + lane] = qc.x;    shh[832 + lane] = qd.x;
          shh[896 + lane] = qe.x;    shh[960 + lane] = qf.x;
        }
      } else if (tid == 128) {
        // dense partial for step t (wave2 lane0; parallel with pub+poll)
        float s = 0.f;
#pragma unroll
        for (int wv = 0; wv < 8; ++wv) s += psm[wv];
        yp[t * 64 + b] = s;
      }
      __syncthreads();  // bar2
    }
  }
}

__global__ void esn_out(const float* __restrict__ X,
                        const float* __restrict__ wtil,
                        const float* __restrict__ yp,
                        const float* __restrict__ bptr,
                        float* __restrict__ out) {
  const int tid = threadIdx.x;
  const int lane = tid & 63;
  const int wave = tid >> 6;
  const int t = blockIdx.x * 4 + wave;
  float v = wtil[lane] * X[t * 64 + lane] + yp[t * 64 + lane];
#pragma unroll
  for (int off = 32; off; off >>= 1) v += __shfl_xor(v, off, 64);
  if (lane == 0) out[t] = v + bptr[0];
}

extern "C" void kernel_launch(void* const* d_in, const int* in_sizes, int n_in,
                              void* d_out, int out_size, void* d_ws, size_t ws_size,
                              hipStream_t stream) {
  const float* X   = (const float*)d_in[0];
  const float* C   = (const float*)d_in[1];
  const float* Win = (const float*)d_in[2];
  const float* W   = (const float*)d_in[3];
  const float* dW  = (const float*)d_in[4];
  const float* db  = (const float*)d_in[5];
  float* ws   = (float*)d_ws;
  float* M    = ws;
  float* wtil = ws + 131072;
  float* yp   = ws + 131200;
  unsigned int* hpub = (unsigned int*)(ws + 393344);

  esn_prep<<<2049, 64, 0, stream>>>(C, Win, dW, M, wtil);

  void* args[] = {(void*)&X, (void*)&M, (void*)&W, (void*)&dW,
                  (void*)&hpub, (void*)&yp};
  (void)hipLaunchCooperativeKernel(reinterpret_cast<void*>(&esn_recur), dim3(64),
                                   dim3(1024), args, 0, stream);

  esn_out<<<1024, 256, 0, stream>>>(X, wtil, yp, db, (float*)d_out);
}